// Round 1
// baseline (199.954 us; speedup 1.0000x reference)
//
#include <hip/hip_runtime.h>

// Augmenter: B=128, C=3, H=W=256, fp32.
// out_c = c2*s2*(x_c - cm) + c2*(cm - gm) + gm + b1   (color ops fused)
// then translate (zero pad) on source coords, cutout rect (zero) on dest coords.
constexpr int BN  = 128;
constexpr int CN  = 3;
constexpr int HN  = 256;
constexpr int WN  = 256;
constexpr int HW  = HN * WN;       // 65536
constexpr int CHW = CN * HW;       // 196608
constexpr int SHIFT_ = 32;         // int(H*0.125+0.5)
constexpr int CS  = 128;           // int(H*0.5+0.5)
constexpr int RBLK = 8;            // reduce blocks per batch

// --- Kernel 1: per-batch partial sums (for global mean) -------------------
__global__ __launch_bounds__(256) void aug_reduce(const float* __restrict__ x,
                                                  float* __restrict__ partial) {
    const int j = blockIdx.x;          // chunk within batch, 0..RBLK-1
    const int b = blockIdx.y;          // batch
    const int t = threadIdx.x;
    constexpr int PER_BLOCK = CHW / 4 / RBLK;   // 6144 float4 per block
    const float4* p = reinterpret_cast<const float4*>(x + (size_t)b * CHW)
                      + (size_t)j * PER_BLOCK;
    float s = 0.f;
    for (int i = t; i < PER_BLOCK; i += 256) {
        float4 v = p[i];
        s += (v.x + v.y) + (v.z + v.w);
    }
    __shared__ float sm[256];
    sm[t] = s;
    __syncthreads();
    #pragma unroll
    for (int off = 128; off > 0; off >>= 1) {
        if (t < off) sm[t] += sm[t + off];
        __syncthreads();
    }
    if (t == 0) partial[b * RBLK + j] = sm[0];
}

// --- Kernel 2: fused color transform + translate + cutout -----------------
__global__ __launch_bounds__(256) void aug_apply(
    const float* __restrict__ x,
    const float* __restrict__ br, const float* __restrict__ sat,
    const float* __restrict__ con,
    const int* __restrict__ tx, const int* __restrict__ ty,
    const int* __restrict__ cx, const int* __restrict__ cy,
    const float* __restrict__ partial, float* __restrict__ out)
{
    const int b = blockIdx.y;
    const int p = blockIdx.x * 256 + threadIdx.x;   // pixel index 0..HW-1
    const int h = p >> 8;
    const int w = p & (WN - 1);

    // global mean for this batch (sum of RBLK partials), broadcast via LDS
    __shared__ float s_gm;
    if (threadIdx.x == 0) {
        float s = 0.f;
        #pragma unroll
        for (int i = 0; i < RBLK; ++i) s += partial[b * RBLK + i];
        s_gm = s * (1.0f / (float)CHW);
    }
    __syncthreads();
    const float gm = s_gm;

    const float b1 = br[b] - 0.5f;
    const float s2 = sat[b] * 2.0f;
    const float c2 = con[b] + 0.5f;

    // translation source coords (zero outside [0,H)x[0,W))
    const int sh = h + (tx[b] - SHIFT_);
    const int sw = w + (ty[b] - SHIFT_);
    // cutout rect on destination coords
    const int cx0 = cx[b] - CS / 2;
    const int cy0 = cy[b] - CS / 2;
    const int h0 = max(cx0, 0), h1 = min(cx0 + CS - 1, HN - 1);
    const int w0 = max(cy0, 0), w1 = min(cy0 + CS - 1, WN - 1);

    float o0 = 0.f, o1 = 0.f, o2 = 0.f;
    const bool cut = (h >= h0) & (h <= h1) & (w >= w0) & (w <= w1);
    const bool oob = (sh < 0) | (sh >= HN) | (sw < 0) | (sw >= WN);
    if (!(cut | oob)) {
        const int base = b * CHW + sh * WN + sw;
        const float x0 = x[base];
        const float x1 = x[base + HW];
        const float x2 = x[base + 2 * HW];
        const float cm  = (x0 + x1 + x2) * (1.0f / 3.0f);
        const float add = c2 * (cm - gm) + gm + b1;   // c2*(cm-gm)+gm+b1
        const float k   = c2 * s2;
        o0 = k * (x0 - cm) + add;
        o1 = k * (x1 - cm) + add;
        o2 = k * (x2 - cm) + add;
    }
    const int ob = b * CHW + p;
    out[ob]          = o0;
    out[ob + HW]     = o1;
    out[ob + 2 * HW] = o2;
}

extern "C" void kernel_launch(void* const* d_in, const int* in_sizes, int n_in,
                              void* d_out, int out_size, void* d_ws, size_t ws_size,
                              hipStream_t stream) {
    const float* imgs = (const float*)d_in[0];
    const float* br   = (const float*)d_in[1];
    const float* sat  = (const float*)d_in[2];
    const float* con  = (const float*)d_in[3];
    const int*   tx   = (const int*)d_in[4];
    const int*   ty   = (const int*)d_in[5];
    const int*   cx   = (const int*)d_in[6];
    const int*   cy   = (const int*)d_in[7];
    float* out = (float*)d_out;
    float* partial = (float*)d_ws;   // BN*RBLK floats = 4 KiB

    aug_reduce<<<dim3(RBLK, BN), 256, 0, stream>>>(imgs, partial);
    aug_apply<<<dim3(HW / 256, BN), 256, 0, stream>>>(imgs, br, sat, con,
                                                      tx, ty, cx, cy, partial, out);
}

// Round 2
// 198.478 us; speedup vs baseline: 1.0074x; 1.0074x over previous
//
#include <hip/hip_runtime.h>

// Augmenter: B=128, C=3, H=W=256, fp32.
// out_c = c2*s2*(x_c - cm) + c2*(cm - gm) + gm + b1   (color ops fused)
// then translate (zero pad) on source coords, cutout rect (zero) on dest coords.
constexpr int BN  = 128;
constexpr int CN  = 3;
constexpr int HN  = 256;
constexpr int WN  = 256;
constexpr int HW  = HN * WN;       // 65536
constexpr int CHW = CN * HW;       // 196608
constexpr int SHIFT_ = 32;         // int(H*0.125+0.5)
constexpr int CS  = 128;           // int(H*0.5+0.5)
constexpr int RBLK = 8;            // reduce blocks per batch

// --- Kernel 1: per-batch partial sums (for global mean) -------------------
__global__ __launch_bounds__(256) void aug_reduce(const float* __restrict__ x,
                                                  float* __restrict__ partial) {
    const int j = blockIdx.x;          // chunk within batch, 0..RBLK-1
    const int b = blockIdx.y;          // batch
    const int t = threadIdx.x;
    constexpr int PER_BLOCK = CHW / 4 / RBLK;   // 6144 float4 per block
    const float4* p = reinterpret_cast<const float4*>(x + (size_t)b * CHW)
                      + (size_t)j * PER_BLOCK;
    float s = 0.f;
    for (int i = t; i < PER_BLOCK; i += 256) {
        float4 v = p[i];
        s += (v.x + v.y) + (v.z + v.w);
    }
    __shared__ float sm[256];
    sm[t] = s;
    __syncthreads();
    #pragma unroll
    for (int off = 128; off > 0; off >>= 1) {
        if (t < off) sm[t] += sm[t + off];
        __syncthreads();
    }
    if (t == 0) partial[b * RBLK + j] = sm[0];
}

// --- Kernel 2: fused color transform + translate + cutout, 4 px/thread ----
__global__ __launch_bounds__(256) void aug_apply(
    const float* __restrict__ x,
    const float* __restrict__ br, const float* __restrict__ sat,
    const float* __restrict__ con,
    const int* __restrict__ tx, const int* __restrict__ ty,
    const int* __restrict__ cx, const int* __restrict__ cy,
    const float* __restrict__ partial, float* __restrict__ out)
{
    const int b  = blockIdx.y;
    const int g  = blockIdx.x * 256 + threadIdx.x;   // float4-group index
    const int p0 = g << 2;                           // first pixel of group
    const int h  = p0 >> 8;                          // row (same for all 4)
    const int w0 = p0 & (WN - 1);                    // first col

    // global mean for this batch (sum of RBLK partials), broadcast via LDS
    __shared__ float s_gm;
    if (threadIdx.x == 0) {
        float s = 0.f;
        #pragma unroll
        for (int i = 0; i < RBLK; ++i) s += partial[b * RBLK + i];
        s_gm = s * (1.0f / (float)CHW);
    }
    __syncthreads();
    const float gm = s_gm;

    const float b1 = br[b] - 0.5f;
    const float k  = (con[b] + 0.5f) * (sat[b] * 2.0f);   // c2*s2
    const float c2 = con[b] + 0.5f;

    // translation source coords (zero outside [0,H)x[0,W))
    const int sh  = h  + (tx[b] - SHIFT_);
    const int sw0 = w0 + (ty[b] - SHIFT_);
    // cutout rect on destination coords
    const int cx0 = cx[b] - CS / 2;
    const int cy0 = cy[b] - CS / 2;
    const int h0 = max(cx0, 0), h1 = min(cx0 + CS - 1, HN - 1);
    const int wc0 = max(cy0, 0), wc1 = min(cy0 + CS - 1, WN - 1);

    const bool rowok   = (sh >= 0) & (sh < HN);
    const bool cut_row = (h >= h0) & (h <= h1);
    const bool cut_all = cut_row & (w0 >= wc0) & (w0 + 3 <= wc1);

    float x0[4], x1[4], x2[4];
    bool  valid[4];

    if (rowok & !cut_all) {
        const float* base = x + (size_t)b * CHW + sh * WN + sw0;
        if (sw0 >= 0 && sw0 + 3 < WN) {
            // fast path: 16-B (dword-aligned) vector loads per channel
            float4 a, bb, c;
            __builtin_memcpy(&a,  base,          sizeof(float4));
            __builtin_memcpy(&bb, base + HW,     sizeof(float4));
            __builtin_memcpy(&c,  base + 2 * HW, sizeof(float4));
            x0[0]=a.x;  x0[1]=a.y;  x0[2]=a.z;  x0[3]=a.w;
            x1[0]=bb.x; x1[1]=bb.y; x1[2]=bb.z; x1[3]=bb.w;
            x2[0]=c.x;  x2[1]=c.y;  x2[2]=c.z;  x2[3]=c.w;
            #pragma unroll
            for (int i = 0; i < 4; ++i) valid[i] = true;
        } else {
            // row-edge fallback: masked scalar loads
            #pragma unroll
            for (int i = 0; i < 4; ++i) {
                const int sw = sw0 + i;
                const bool ok = (sw >= 0) & (sw < WN);
                valid[i] = ok;
                if (ok) {
                    x0[i] = base[i];
                    x1[i] = base[i + HW];
                    x2[i] = base[i + 2 * HW];
                } else {
                    x0[i] = x1[i] = x2[i] = 0.f;
                }
            }
        }
    } else {
        #pragma unroll
        for (int i = 0; i < 4; ++i) { x0[i]=x1[i]=x2[i]=0.f; valid[i]=false; }
    }

    float4 o0, o1, o2;
    float* po0 = &o0.x; float* po1 = &o1.x; float* po2 = &o2.x;
    #pragma unroll
    for (int i = 0; i < 4; ++i) {
        const int w = w0 + i;
        const bool cut = cut_row & (w >= wc0) & (w <= wc1);
        const bool live = valid[i] & !cut;
        const float cm  = (x0[i] + x1[i] + x2[i]) * (1.0f / 3.0f);
        const float add = c2 * (cm - gm) + gm + b1;
        po0[i] = live ? (k * (x0[i] - cm) + add) : 0.f;
        po1[i] = live ? (k * (x1[i] - cm) + add) : 0.f;
        po2[i] = live ? (k * (x2[i] - cm) + add) : 0.f;
    }

    float4* ob = reinterpret_cast<float4*>(out + (size_t)b * CHW + p0);
    ob[0]          = o0;
    ob[HW / 4]     = o1;
    ob[2 * HW / 4] = o2;
}

extern "C" void kernel_launch(void* const* d_in, const int* in_sizes, int n_in,
                              void* d_out, int out_size, void* d_ws, size_t ws_size,
                              hipStream_t stream) {
    const float* imgs = (const float*)d_in[0];
    const float* br   = (const float*)d_in[1];
    const float* sat  = (const float*)d_in[2];
    const float* con  = (const float*)d_in[3];
    const int*   tx   = (const int*)d_in[4];
    const int*   ty   = (const int*)d_in[5];
    const int*   cx   = (const int*)d_in[6];
    const int*   cy   = (const int*)d_in[7];
    float* out = (float*)d_out;
    float* partial = (float*)d_ws;   // BN*RBLK floats = 4 KiB

    aug_reduce<<<dim3(RBLK, BN), 256, 0, stream>>>(imgs, partial);
    aug_apply<<<dim3(HW / 4 / 256, BN), 256, 0, stream>>>(imgs, br, sat, con,
                                                          tx, ty, cx, cy, partial, out);
}